// Round 5
// baseline (1057.124 us; speedup 1.0000x reference)
//
#include <hip/hip_runtime.h>

#define T_TOK 4096
#define H_DIM 2048
#define I_DIM 1408
#define E_NUM 8
#define NI2   (2 * I_DIM)   // 2816

typedef int v4i __attribute__((ext_vector_type(4)));

// ---------------------------------------------------------------------------
// Pack int32 -> int8 for both weight tensors in one launch
// ---------------------------------------------------------------------------
__global__ __launch_bounds__(256) void pack_all(const int* __restrict__ w13,
                                                const int* __restrict__ w2,
                                                signed char* __restrict__ qw13,
                                                signed char* __restrict__ qw2,
                                                int n16a, int n16tot) {
  int i = blockIdx.x * 256 + threadIdx.x;
  if (i >= n16tot) return;
  const int* src;
  signed char* dst;
  int j;
  if (i < n16a) { src = w13; dst = qw13; j = i; }
  else          { src = w2;  dst = qw2;  j = i - n16a; }
  const int4* s4 = (const int4*)src + (size_t)j * 4;
  int4 v0 = s4[0], v1 = s4[1], v2 = s4[2], v3 = s4[3];
  union { signed char c[16]; int4 v; } pk;
  pk.c[0] = (signed char)v0.x;  pk.c[1] = (signed char)v0.y;
  pk.c[2] = (signed char)v0.z;  pk.c[3] = (signed char)v0.w;
  pk.c[4] = (signed char)v1.x;  pk.c[5] = (signed char)v1.y;
  pk.c[6] = (signed char)v1.z;  pk.c[7] = (signed char)v1.w;
  pk.c[8] = (signed char)v2.x;  pk.c[9] = (signed char)v2.y;
  pk.c[10] = (signed char)v2.z; pk.c[11] = (signed char)v2.w;
  pk.c[12] = (signed char)v3.x; pk.c[13] = (signed char)v3.y;
  pk.c[14] = (signed char)v3.z; pk.c[15] = (signed char)v3.w;
  ((int4*)dst)[j] = pk.v;
}

// ---------------------------------------------------------------------------
// Gate logits + top-2 + dynamic int8 quant.
// ---------------------------------------------------------------------------
__global__ __launch_bounds__(256) void gate_route_quant(
    const float* __restrict__ hs, const float* __restrict__ gw,
    signed char* __restrict__ qin, float* __restrict__ s_in,
    int* __restrict__ tope, float* __restrict__ gts) {
  const int t = blockIdx.x;
  const int tid = threadIdx.x;
  const int lane = tid & 63;
  const int wave = tid >> 6;
  const float* row = hs + (size_t)t * H_DIM;

  const float4* r4 = (const float4*)row + tid * 2;
  float4 xa = r4[0], xb = r4[1];
  float x[8] = {xa.x, xa.y, xa.z, xa.w, xb.x, xb.y, xb.z, xb.w};

  double pd[8];
  for (int e = 0; e < 8; e++) pd[e] = 0.0;
  float am = 0.f;
  for (int j = 0; j < 8; j++) {
    float v = x[j];
    am = fmaxf(am, fabsf(v));
    int col = tid * 8 + j;
    for (int e = 0; e < 8; e++)
      pd[e] += (double)v * (double)gw[e * H_DIM + col];
  }
  for (int e = 0; e < 8; e++)
    for (int s = 32; s; s >>= 1) pd[e] += __shfl_down(pd[e], s);
  for (int s = 32; s; s >>= 1) am = fmaxf(am, __shfl_down(am, s));

  __shared__ double sred[4][8];
  __shared__ float sam[4];
  __shared__ float sbc;
  if (lane == 0) {
    for (int e = 0; e < 8; e++) sred[wave][e] = pd[e];
    sam[wave] = am;
  }
  __syncthreads();
  if (tid == 0) {
    float l[8];
    for (int e = 0; e < 8; e++)
      l[e] = (float)(sred[0][e] + sred[1][e] + sred[2][e] + sred[3][e]);
    float amx = fmaxf(fmaxf(sam[0], sam[1]), fmaxf(sam[2], sam[3]));
    float s = fmaxf(amx / 127.0f, 1e-8f);
    s_in[t] = s;
    sbc = s;
    int i1 = 0;
    for (int e = 1; e < 8; e++) if (l[e] > l[i1]) i1 = e;
    int i2 = -1;
    for (int e = 0; e < 8; e++) {
      if (e == i1) continue;
      if (i2 < 0 || l[e] > l[i2]) i2 = e;
    }
    float d = expf(l[i2] - l[i1]);
    tope[2 * t] = i1;     gts[2 * t] = 1.0f / (1.0f + d);
    tope[2 * t + 1] = i2; gts[2 * t + 1] = d / (1.0f + d);
  }
  __syncthreads();
  float s = sbc;
  union { signed char c[8]; unsigned long long u; } pk;
  for (int j = 0; j < 8; j++) {
    float q = rintf(x[j] / s);
    q = fminf(127.f, fmaxf(-127.f, q));
    pk.c[j] = (signed char)q;
  }
  ((unsigned long long*)(qin + (size_t)t * H_DIM))[tid] = pk.u;
}

// ---------------------------------------------------------------------------
// Build per-expert token lists deterministically (ballot prefix, no atomics).
// ---------------------------------------------------------------------------
__global__ __launch_bounds__(256) void build_lists(
    const int* __restrict__ tope, int* __restrict__ tok_list,
    int* __restrict__ epos, int* __restrict__ cnt) {
  const int e = blockIdx.x;
  const int tid = threadIdx.x;
  const int lane = tid & 63;
  const int wave = tid >> 6;
  __shared__ int wsum[4];
  __shared__ int base_s;
  if (tid == 0) base_s = 0;
  __syncthreads();
  for (int t0 = 0; t0 < T_TOK; t0 += 256) {
    int t = t0 + tid;
    int i1 = tope[2 * t], i2 = tope[2 * t + 1];
    int slot = (i1 == e) ? 0 : ((i2 == e) ? 1 : -1);
    unsigned long long m = __ballot(slot >= 0);
    int wpre = __popcll(m & ((1ull << lane) - 1ull));
    if (lane == 0) wsum[wave] = __popcll(m);
    __syncthreads();
    int pre = wpre;
    for (int w = 0; w < wave; w++) pre += wsum[w];
    int total = wsum[0] + wsum[1] + wsum[2] + wsum[3];
    int b = base_s;
    if (slot >= 0) {
      int pos = b + pre;
      tok_list[e * T_TOK + pos] = t;
      epos[2 * t + slot] = (e << 16) | pos;
    }
    __syncthreads();
    if (tid == 0) base_s = b + total;
  }
  __syncthreads();
  if (tid == 0) cnt[e] = base_s;
}

__global__ void calc_off(const int* __restrict__ cnt, int* __restrict__ off) {
  if (threadIdx.x == 0) {
    int s = 0;
    for (int e = 0; e < E_NUM; e++) { off[e] = s; s += cnt[e]; }
  }
}

// ---------------------------------------------------------------------------
// GEMM1 (flat, no LDS, no barriers): per wave M=64 x N=32 (g and u).
// A fragments from global via L1 (shared across the block's 4 waves);
// B fragments streamed global->VGPR. Register double-buffer, unroll x2.
// ---------------------------------------------------------------------------
__global__ __launch_bounds__(256, 3) void gemm1_silu(
    const signed char* __restrict__ qw13, const signed char* __restrict__ qin,
    const float* __restrict__ s_in, const float* __restrict__ s13,
    const int* __restrict__ tok_list, const int* __restrict__ cnt,
    const int* __restrict__ off, float* __restrict__ act,
    unsigned int* __restrict__ amax) {
  const int e = blockIdx.z;
  const int ce = cnt[e];
  const int m0 = blockIdx.x * 64;          // m innermost: B-slice L2 reuse
  if (m0 >= ce) return;
  const int wave = threadIdx.x >> 6;
  const int lane = threadIdx.x & 63;
  const int quad = lane >> 4;
  const int ln = lane & 15;
  const int n0 = blockIdx.y * 128 + wave * 32;   // this wave's 32 g-cols

  const int* tl = tok_list + e * T_TOK;
  const signed char* w13e = qw13 + (size_t)e * NI2 * H_DIM;

  const signed char* ap[4];
#pragma unroll
  for (int mt = 0; mt < 4; mt++) {
    int mrel = min(m0 + mt * 16 + ln, ce - 1);
    ap[mt] = qin + (size_t)tl[mrel] * H_DIM + quad * 16;
  }
  const signed char* bgp[2];
  const signed char* bup[2];
#pragma unroll
  for (int nt = 0; nt < 2; nt++) {
    bgp[nt] = w13e + (size_t)(n0 + nt * 16 + ln) * H_DIM + quad * 16;
    bup[nt] = bgp[nt] + (size_t)I_DIM * H_DIM;
  }

  v4i accg[4][2], accu[4][2];
  v4i zero = {0, 0, 0, 0};
#pragma unroll
  for (int i = 0; i < 4; i++)
#pragma unroll
    for (int j = 0; j < 2; j++) { accg[i][j] = zero; accu[i][j] = zero; }

  v4i aA[4], gA[2], uA[2];   // buffer A
  v4i aB[4], gB[2], uB[2];   // buffer B

#define LOADSET(Ar, Gr, Ur, K)                                         \
  {                                                                    \
    _Pragma("unroll") for (int mt = 0; mt < 4; mt++)                   \
        Ar[mt] = *(const v4i*)(ap[mt] + (K));                          \
    _Pragma("unroll") for (int nt = 0; nt < 2; nt++) {                 \
      Gr[nt] = *(const v4i*)(bgp[nt] + (K));                           \
      Ur[nt] = *(const v4i*)(bup[nt] + (K));                           \
    }                                                                  \
  }
#define MFMASET(Ar, Gr, Ur)                                            \
  {                                                                    \
    _Pragma("unroll") for (int mt = 0; mt < 4; mt++)                   \
        _Pragma("unroll") for (int nt = 0; nt < 2; nt++) {             \
      accg[mt][nt] = __builtin_amdgcn_mfma_i32_16x16x64_i8(            \
          Ar[mt], Gr[nt], accg[mt][nt], 0, 0, 0);                      \
      accu[mt][nt] = __builtin_amdgcn_mfma_i32_16x16x64_i8(            \
          Ar[mt], Ur[nt], accu[mt][nt], 0, 0, 0);                      \
    }                                                                  \
  }

  LOADSET(aA, gA, uA, 0)
  for (int k0 = 0; k0 < H_DIM; k0 += 128) {
    LOADSET(aB, gB, uB, k0 + 64)
    MFMASET(aA, gA, uA)
    if (k0 + 128 < H_DIM) LOADSET(aA, gA, uA, k0 + 128)
    MFMASET(aB, gB, uB)
  }
#undef LOADSET
#undef MFMASET

  const float* s13e = s13 + e * NI2;
  float sg[2], su[2];
  int ncol[2];
#pragma unroll
  for (int nt = 0; nt < 2; nt++) {
    int n = n0 + nt * 16 + ln;
    ncol[nt] = n;
    sg[nt] = s13e[n];
    su[nt] = s13e[I_DIM + n];
  }
  const int offe = off[e];
#pragma unroll
  for (int mt = 0; mt < 4; mt++) {
#pragma unroll
    for (int r = 0; r < 4; r++) {
      int mrel = m0 + mt * 16 + quad * 4 + r;
      bool valid = mrel < ce;
      int tok = tl[valid ? mrel : 0];
      float si = s_in[tok];
      int crow = offe + mrel;
      float* arow = act + (size_t)crow * I_DIM;
      float am = 0.f;
#pragma unroll
      for (int nt = 0; nt < 2; nt++) {
        float g = (float)accg[mt][nt][r] * si * sg[nt];
        float u = (float)accu[mt][nt][r] * si * su[nt];
        float a = g / (1.0f + expf(-g)) * u;
        if (valid) arow[ncol[nt]] = a;
        am = fmaxf(am, fabsf(a));
      }
      for (int s = 1; s < 16; s <<= 1) am = fmaxf(am, __shfl_xor(am, s, 16));
      if (valid && ln == 0) atomicMax(amax + crow, __float_as_uint(am));
    }
  }
}

// ---------------------------------------------------------------------------
// Per-row dynamic int8 quant of act
// ---------------------------------------------------------------------------
__global__ __launch_bounds__(256) void quant_act(const float* __restrict__ act,
                                                 const unsigned int* __restrict__ amax,
                                                 signed char* __restrict__ qa,
                                                 float* __restrict__ s_a) {
  const int r = blockIdx.x;
  float am = __uint_as_float(amax[r]);
  float s = fmaxf(am / 127.0f, 1e-8f);
  if (threadIdx.x == 0) s_a[r] = s;
  const float* arow = act + (size_t)r * I_DIM;
  signed char* qrow = qa + (size_t)r * I_DIM;
  for (int j = threadIdx.x; j < I_DIM; j += 256) {
    float q = rintf(arow[j] / s);
    q = fminf(127.f, fmaxf(-127.f, q));
    qrow[j] = (signed char)q;
  }
}

// ---------------------------------------------------------------------------
// GEMM2 (flat): per wave M=64 x N=32, K=1408. h2s plain stores.
// ---------------------------------------------------------------------------
__global__ __launch_bounds__(256, 4) void gemm2_h2(
    const signed char* __restrict__ qw2, const signed char* __restrict__ qa,
    const float* __restrict__ s_a, const float* __restrict__ s2w,
    const int* __restrict__ cnt, const int* __restrict__ off,
    float* __restrict__ h2s) {
  const int e = blockIdx.z;
  const int ce = cnt[e];
  const int m0 = blockIdx.x * 64;
  if (m0 >= ce) return;
  const int offe = off[e];
  const int wave = threadIdx.x >> 6;
  const int lane = threadIdx.x & 63;
  const int quad = lane >> 4;
  const int ln = lane & 15;
  const int n0 = blockIdx.y * 128 + wave * 32;

  const signed char* w2e = qw2 + (size_t)e * H_DIM * I_DIM;

  const signed char* ap[4];
#pragma unroll
  for (int mt = 0; mt < 4; mt++) {
    int mrel = min(m0 + mt * 16 + ln, ce - 1);
    ap[mt] = qa + (size_t)(offe + mrel) * I_DIM + quad * 16;
  }
  const signed char* bp[2];
#pragma unroll
  for (int nt = 0; nt < 2; nt++)
    bp[nt] = w2e + (size_t)(n0 + nt * 16 + ln) * I_DIM + quad * 16;

  v4i acc[4][2];
  v4i zero = {0, 0, 0, 0};
#pragma unroll
  for (int i = 0; i < 4; i++)
#pragma unroll
    for (int j = 0; j < 2; j++) acc[i][j] = zero;

  v4i aA[4], bA[2], aB[4], bB[2];

#define LOADSET2(Ar, Br, K)                                            \
  {                                                                    \
    _Pragma("unroll") for (int mt = 0; mt < 4; mt++)                   \
        Ar[mt] = *(const v4i*)(ap[mt] + (K));                          \
    _Pragma("unroll") for (int nt = 0; nt < 2; nt++)                   \
        Br[nt] = *(const v4i*)(bp[nt] + (K));                          \
  }
#define MFMASET2(Ar, Br)                                               \
  {                                                                    \
    _Pragma("unroll") for (int mt = 0; mt < 4; mt++)                   \
        _Pragma("unroll") for (int nt = 0; nt < 2; nt++)               \
            acc[mt][nt] = __builtin_amdgcn_mfma_i32_16x16x64_i8(       \
                Ar[mt], Br[nt], acc[mt][nt], 0, 0, 0);                 \
  }

  LOADSET2(aA, bA, 0)
  for (int k0 = 0; k0 < I_DIM; k0 += 128) {
    LOADSET2(aB, bB, k0 + 64)
    MFMASET2(aA, bA)
    if (k0 + 128 < I_DIM) LOADSET2(aA, bA, k0 + 128)
    MFMASET2(aB, bB)
  }
#undef LOADSET2
#undef MFMASET2

  const float* s2e = s2w + e * H_DIM;
  float sw[2];
  int ncol[2];
#pragma unroll
  for (int nt = 0; nt < 2; nt++) {
    int n = n0 + nt * 16 + ln;
    ncol[nt] = n;
    sw[nt] = s2e[n];
  }
#pragma unroll
  for (int mt = 0; mt < 4; mt++) {
#pragma unroll
    for (int r = 0; r < 4; r++) {
      int mrel = m0 + mt * 16 + quad * 4 + r;
      if (mrel >= ce) continue;
      float sa = s_a[offe + mrel];
      float* orow = h2s + (size_t)(offe + mrel) * H_DIM;
#pragma unroll
      for (int nt = 0; nt < 2; nt++)
        orow[ncol[nt]] = (float)acc[mt][nt][r] * sa * sw[nt];
    }
  }
}

// ---------------------------------------------------------------------------
// Final gather: out[t] = g1 * h2s[r1] + g2 * h2s[r2]
// ---------------------------------------------------------------------------
__global__ __launch_bounds__(256) void gather_out(
    const float* __restrict__ h2s, const int* __restrict__ epos,
    const float* __restrict__ gts, const int* __restrict__ off,
    float* __restrict__ out) {
  const int t = blockIdx.x;
  int a = epos[2 * t], b = epos[2 * t + 1];
  float g1 = gts[2 * t], g2 = gts[2 * t + 1];
  int r1 = off[a >> 16] + (a & 0xffff);
  int r2 = off[b >> 16] + (b & 0xffff);
  const float4* R1 = (const float4*)(h2s + (size_t)r1 * H_DIM);
  const float4* R2 = (const float4*)(h2s + (size_t)r2 * H_DIM);
  float4* O = (float4*)(out + (size_t)t * H_DIM);
  for (int c = threadIdx.x; c < H_DIM / 4; c += 256) {
    float4 x = R1[c], y = R2[c];
    float4 z;
    z.x = g1 * x.x + g2 * y.x;
    z.y = g1 * x.y + g2 * y.y;
    z.z = g1 * x.z + g2 * y.z;
    z.w = g1 * x.w + g2 * y.w;
    O[c] = z;
  }
}

// ---------------------------------------------------------------------------
extern "C" void kernel_launch(void* const* d_in, const int* in_sizes, int n_in,
                              void* d_out, int out_size, void* d_ws, size_t ws_size,
                              hipStream_t stream) {
  const float* hs = (const float*)d_in[0];
  const float* gw = (const float*)d_in[1];
  const int* w13 = (const int*)d_in[2];
  const float* s13 = (const float*)d_in[3];
  const int* w2 = (const int*)d_in[4];
  const float* s2w = (const float*)d_in[5];
  float* out = (float*)d_out;

  char* ws = (char*)d_ws;
  size_t o = 0;
  auto take = [&](size_t b) {
    char* p = ws + o;
    o += (b + 255) & ~(size_t)255;
    return p;
  };
  signed char* qw13 = (signed char*)take((size_t)E_NUM * NI2 * H_DIM);       // 46.1 MB
  signed char* qin = (signed char*)take((size_t)T_TOK * H_DIM);              // 8.4 MB
  float* act = (float*)take((size_t)T_TOK * 2 * I_DIM * 4);                  // 46.1 MB
  float* h2s = (float*)qw13;  // aliases dead qw13+qin+act space (67.1 MB needed)
  signed char* qw2 = (signed char*)take((size_t)E_NUM * H_DIM * I_DIM);      // 23.1 MB
  signed char* qa = (signed char*)take((size_t)T_TOK * 2 * I_DIM);           // 11.5 MB
  float* sin_ = (float*)take((size_t)T_TOK * 4);
  float* sa = (float*)take((size_t)T_TOK * 2 * 4);
  unsigned int* amax = (unsigned int*)take((size_t)T_TOK * 2 * 4);
  int* tokl = (int*)take((size_t)E_NUM * T_TOK * 4);
  int* tope = (int*)take((size_t)T_TOK * 2 * 4);
  int* epos = (int*)take((size_t)T_TOK * 2 * 4);
  float* gts = (float*)take((size_t)T_TOK * 2 * 4);
  int* cnt = (int*)take(E_NUM * 4);
  int* off = (int*)take(E_NUM * 4);

  hipMemsetAsync(amax, 0, (size_t)T_TOK * 2 * 4, stream);

  {
    int n16a = E_NUM * NI2 * H_DIM / 16;
    int n16b = E_NUM * H_DIM * I_DIM / 16;
    int n16tot = n16a + n16b;
    pack_all<<<(n16tot + 255) / 256, 256, 0, stream>>>(w13, w2, qw13, qw2, n16a, n16tot);
  }
  gate_route_quant<<<T_TOK, 256, 0, stream>>>(hs, gw, qin, sin_, tope, gts);
  build_lists<<<E_NUM, 256, 0, stream>>>(tope, tokl, epos, cnt);
  calc_off<<<1, 64, 0, stream>>>(cnt, off);
  {
    dim3 g(T_TOK / 64, I_DIM / 128, E_NUM);
    gemm1_silu<<<g, 256, 0, stream>>>(qw13, qin, sin_, s13, tokl, cnt, off, act, amax);
  }
  quant_act<<<T_TOK * 2, 256, 0, stream>>>(act, amax, qa, sa);
  {
    dim3 g(T_TOK / 64, H_DIM / 128, E_NUM);
    gemm2_h2<<<g, 256, 0, stream>>>(qw2, qa, sa, s2w, cnt, off, h2s);
  }
  gather_out<<<T_TOK, 256, 0, stream>>>(h2s, epos, gts, off, out);
}

// Round 6
// 672.400 us; speedup vs baseline: 1.5722x; 1.5722x over previous
//
#include <hip/hip_runtime.h>
#include <hip/hip_bf16.h>

#define T_TOK 4096
#define H_DIM 2048
#define I_DIM 1408
#define E_NUM 8
#define NI2   (2 * I_DIM)   // 2816
#define NMB   136           // max padded m-blocks (8192/64 + 7 partials + safety)

typedef int v4i __attribute__((ext_vector_type(4)));

#define GLD_LDS16(gptr, lptr)                                                        \
  __builtin_amdgcn_global_load_lds(                                                  \
      (const __attribute__((address_space(1))) void*)(gptr),                         \
      (__attribute__((address_space(3))) void*)(lptr), 16, 0, 0)

// ---------------------------------------------------------------------------
// Pack int32 -> int8, TILED: [128 rows][64 k] tiles of 8 KB, contiguous.
// w13: e(8) x nb(22) x kc(32) ; w2: e(8) x nb(16) x kc(22)
// ---------------------------------------------------------------------------
__global__ __launch_bounds__(256) void pack_tiled(
    const int* __restrict__ w13, const int* __restrict__ w2,
    signed char* __restrict__ qw13t, signed char* __restrict__ qw2t) {
  const int id = blockIdx.x;
  const int* src;
  signed char* dst;
  int R, Kd, nb, kc, e;
  if (id < 8 * 22 * 32) {
    e = id / (22 * 32);
    int r = id % (22 * 32);
    nb = r / 32; kc = r % 32;
    src = w13; dst = qw13t + (size_t)id * 8192; R = NI2; Kd = H_DIM;
  } else {
    int j = id - 8 * 22 * 32;
    e = j / (16 * 22);
    int r = j % (16 * 22);
    nb = r / 22; kc = r % 22;
    src = w2; dst = qw2t + (size_t)j * 8192; R = H_DIM; Kd = I_DIM;
  }
  const int tid = threadIdx.x;
  const int seg = tid & 3;
#pragma unroll
  for (int h = 0; h < 2; h++) {
    int row = h * 64 + (tid >> 2);
    const int4* s4 = (const int4*)(src + ((size_t)(e * R + nb * 128 + row) * Kd + kc * 64 + seg * 16));
    int4 v0 = s4[0], v1 = s4[1], v2 = s4[2], v3 = s4[3];
    union { signed char c[16]; int4 v; } pk;
    pk.c[0] = (signed char)v0.x;  pk.c[1] = (signed char)v0.y;
    pk.c[2] = (signed char)v0.z;  pk.c[3] = (signed char)v0.w;
    pk.c[4] = (signed char)v1.x;  pk.c[5] = (signed char)v1.y;
    pk.c[6] = (signed char)v1.z;  pk.c[7] = (signed char)v1.w;
    pk.c[8] = (signed char)v2.x;  pk.c[9] = (signed char)v2.y;
    pk.c[10] = (signed char)v2.z; pk.c[11] = (signed char)v2.w;
    pk.c[12] = (signed char)v3.x; pk.c[13] = (signed char)v3.y;
    pk.c[14] = (signed char)v3.z; pk.c[15] = (signed char)v3.w;
    *(int4*)(dst + h * 4096 + tid * 16) = pk.v;
  }
}

// ---------------------------------------------------------------------------
// Gate logits + top-2 + dynamic int8 quant of hidden_states.
// ---------------------------------------------------------------------------
__global__ __launch_bounds__(256) void gate_route_quant(
    const float* __restrict__ hs, const float* __restrict__ gw,
    signed char* __restrict__ qin, float* __restrict__ s_in,
    int* __restrict__ tope, float* __restrict__ gts) {
  const int t = blockIdx.x;
  const int tid = threadIdx.x;
  const int lane = tid & 63;
  const int wave = tid >> 6;
  const float* row = hs + (size_t)t * H_DIM;

  const float4* r4 = (const float4*)row + tid * 2;
  float4 xa = r4[0], xb = r4[1];
  float x[8] = {xa.x, xa.y, xa.z, xa.w, xb.x, xb.y, xb.z, xb.w};

  double pd[8];
  for (int e = 0; e < 8; e++) pd[e] = 0.0;
  float am = 0.f;
  for (int j = 0; j < 8; j++) {
    float v = x[j];
    am = fmaxf(am, fabsf(v));
    int col = tid * 8 + j;
    for (int e = 0; e < 8; e++)
      pd[e] += (double)v * (double)gw[e * H_DIM + col];
  }
  for (int e = 0; e < 8; e++)
    for (int s = 32; s; s >>= 1) pd[e] += __shfl_down(pd[e], s);
  for (int s = 32; s; s >>= 1) am = fmaxf(am, __shfl_down(am, s));

  __shared__ double sred[4][8];
  __shared__ float sam[4];
  __shared__ float sbc;
  if (lane == 0) {
    for (int e = 0; e < 8; e++) sred[wave][e] = pd[e];
    sam[wave] = am;
  }
  __syncthreads();
  if (tid == 0) {
    float l[8];
    for (int e = 0; e < 8; e++)
      l[e] = (float)(sred[0][e] + sred[1][e] + sred[2][e] + sred[3][e]);
    float amx = fmaxf(fmaxf(sam[0], sam[1]), fmaxf(sam[2], sam[3]));
    float s = fmaxf(amx / 127.0f, 1e-8f);
    s_in[t] = s;
    sbc = s;
    int i1 = 0;
    for (int e = 1; e < 8; e++) if (l[e] > l[i1]) i1 = e;
    int i2 = -1;
    for (int e = 0; e < 8; e++) {
      if (e == i1) continue;
      if (i2 < 0 || l[e] > l[i2]) i2 = e;
    }
    float d = expf(l[i2] - l[i1]);
    tope[2 * t] = i1;     gts[2 * t] = 1.0f / (1.0f + d);
    tope[2 * t + 1] = i2; gts[2 * t + 1] = d / (1.0f + d);
  }
  __syncthreads();
  float s = sbc;
  union { signed char c[8]; unsigned long long u; } pk;
  for (int j = 0; j < 8; j++) {
    float q = rintf(x[j] / s);
    q = fminf(127.f, fmaxf(-127.f, q));
    pk.c[j] = (signed char)q;
  }
  ((unsigned long long*)(qin + (size_t)t * H_DIM))[tid] = pk.u;
}

// ---------------------------------------------------------------------------
// Build per-expert token lists deterministically (ballot prefix, no atomics).
// ---------------------------------------------------------------------------
__global__ __launch_bounds__(256) void build_lists(
    const int* __restrict__ tope, int* __restrict__ tok_list,
    int* __restrict__ epos, int* __restrict__ cnt) {
  const int e = blockIdx.x;
  const int tid = threadIdx.x;
  const int lane = tid & 63;
  const int wave = tid >> 6;
  __shared__ int wsum[4];
  __shared__ int base_s;
  if (tid == 0) base_s = 0;
  __syncthreads();
  for (int t0 = 0; t0 < T_TOK; t0 += 256) {
    int t = t0 + tid;
    int i1 = tope[2 * t], i2 = tope[2 * t + 1];
    int slot = (i1 == e) ? 0 : ((i2 == e) ? 1 : -1);
    unsigned long long m = __ballot(slot >= 0);
    int wpre = __popcll(m & ((1ull << lane) - 1ull));
    if (lane == 0) wsum[wave] = __popcll(m);
    __syncthreads();
    int pre = wpre;
    for (int w = 0; w < wave; w++) pre += wsum[w];
    int total = wsum[0] + wsum[1] + wsum[2] + wsum[3];
    int b = base_s;
    if (slot >= 0) {
      int pos = b + pre;
      tok_list[e * T_TOK + pos] = t;
      epos[2 * t + slot] = (e << 16) | pos;
    }
    __syncthreads();
    if (tid == 0) base_s = b + total;
  }
  __syncthreads();
  if (tid == 0) cnt[e] = base_s;
}

__global__ void calc_off(const int* __restrict__ cnt, int* __restrict__ poff) {
  if (threadIdx.x == 0) {
    int p = 0;
    for (int e = 0; e < E_NUM; e++) {
      poff[e] = p;
      p += ((cnt[e] + 63) >> 6) << 6;
    }
  }
}

// ---------------------------------------------------------------------------
// Gather routed token rows into tiled A: qx1[pmb][kc(32)][64 rows][64 B]
// ---------------------------------------------------------------------------
__global__ __launch_bounds__(256) void tile_a1(
    const signed char* __restrict__ qin, const int* __restrict__ tok_list,
    const int* __restrict__ cnt, const int* __restrict__ poff,
    signed char* __restrict__ qx1) {
  const int e = blockIdx.y;
  const int ce = cnt[e];
  const int m0 = blockIdx.x * 64;
  if (m0 >= ce) return;
  const int pmb = (poff[e] >> 6) + blockIdx.x;
  const int tid = threadIdx.x;
  const int row = tid >> 2, seg = tid & 3;
  const int tok = tok_list[e * T_TOK + min(m0 + row, ce - 1)];
  const signed char* src = qin + (size_t)tok * H_DIM + seg * 16;
  signed char* dstb = qx1 + (size_t)pmb * (32 * 4096) + tid * 16;
#pragma unroll
  for (int kc = 0; kc < 32; kc++)
    *(int4*)(dstb + kc * 4096) = *(const int4*)(src + kc * 64);
}

// ---------------------------------------------------------------------------
// GEMM1: 64x128 tile, fully-linear tiled staging, two-barrier K-loop.
// ---------------------------------------------------------------------------
__global__ __launch_bounds__(256, 3) void gemm1_silu(
    const signed char* __restrict__ qw13t, const signed char* __restrict__ qx1,
    const float* __restrict__ s_in, const float* __restrict__ s13,
    const int* __restrict__ tok_list, const int* __restrict__ cnt,
    const int* __restrict__ poff, __hip_bfloat16* __restrict__ act,
    unsigned int* __restrict__ amax) {
  const int e = blockIdx.z;
  const int ce = cnt[e];
  const int m0 = blockIdx.x * 64;
  if (m0 >= ce) return;
  const int nb = blockIdx.y;                 // 0..10
  const int n0 = nb * 128;
  const int pmb = (poff[e] >> 6) + blockIdx.x;

  __shared__ __align__(16) signed char As[4096];
  __shared__ __align__(16) signed char Bg[8192];
  __shared__ __align__(16) signed char Bu[8192];

  const int tid = threadIdx.x;
  const int lane = tid & 63;
  const int wave = tid >> 6;
  const int quad = lane >> 4;
  const int ln = lane & 15;

  const signed char* Ab = qx1 + (size_t)pmb * (32 * 4096) + tid * 16;
  const signed char* Bgb = qw13t + (size_t)(e * 22 + nb) * 32 * 8192 + tid * 16;
  const signed char* Bub = qw13t + (size_t)(e * 22 + nb + 11) * 32 * 8192 + tid * 16;
  const int ldsu = (tid & ~63) * 16;         // wave-uniform LDS base part

  v4i accg[4][2], accu[4][2];
  v4i zero = {0, 0, 0, 0};
#pragma unroll
  for (int i = 0; i < 4; i++)
#pragma unroll
    for (int j = 0; j < 2; j++) { accg[i][j] = zero; accu[i][j] = zero; }

  for (int kc = 0; kc < 32; kc++) {
    __syncthreads();
    GLD_LDS16(Ab + (size_t)kc * 4096, As + ldsu);
    GLD_LDS16(Bgb + (size_t)kc * 8192, Bg + ldsu);
    GLD_LDS16(Bgb + (size_t)kc * 8192 + 4096, Bg + 4096 + ldsu);
    GLD_LDS16(Bub + (size_t)kc * 8192, Bu + ldsu);
    GLD_LDS16(Bub + (size_t)kc * 8192 + 4096, Bu + 4096 + ldsu);
    __syncthreads();

    v4i af[4], bgf[2], buf_[2];
#pragma unroll
    for (int mt = 0; mt < 4; mt++)
      af[mt] = *(const v4i*)(As + (mt * 16 + ln) * 64 + quad * 16);
#pragma unroll
    for (int nt = 0; nt < 2; nt++) {
      bgf[nt] = *(const v4i*)(Bg + (wave * 32 + nt * 16 + ln) * 64 + quad * 16);
      buf_[nt] = *(const v4i*)(Bu + (wave * 32 + nt * 16 + ln) * 64 + quad * 16);
    }
#pragma unroll
    for (int mt = 0; mt < 4; mt++)
#pragma unroll
      for (int nt = 0; nt < 2; nt++) {
        accg[mt][nt] = __builtin_amdgcn_mfma_i32_16x16x64_i8(af[mt], bgf[nt], accg[mt][nt], 0, 0, 0);
        accu[mt][nt] = __builtin_amdgcn_mfma_i32_16x16x64_i8(af[mt], buf_[nt], accu[mt][nt], 0, 0, 0);
      }
  }

  const float* s13e = s13 + e * NI2;
  float sg[2], su[2];
  int ncol[2];
#pragma unroll
  for (int nt = 0; nt < 2; nt++) {
    int n = n0 + wave * 32 + nt * 16 + ln;
    ncol[nt] = n;
    sg[nt] = s13e[n];
    su[nt] = s13e[I_DIM + n];
  }
  const int* tl = tok_list + e * T_TOK;
  const int pbase = poff[e];
#pragma unroll
  for (int mt = 0; mt < 4; mt++) {
#pragma unroll
    for (int r = 0; r < 4; r++) {
      int mrel = m0 + mt * 16 + quad * 4 + r;
      bool valid = mrel < ce;
      int tok = tl[valid ? mrel : 0];
      float si = s_in[tok];
      size_t prow = (size_t)(pbase + mrel);
      __hip_bfloat16* arow = act + prow * I_DIM;
      float am = 0.f;
#pragma unroll
      for (int nt = 0; nt < 2; nt++) {
        float g = (float)accg[mt][nt][r] * si * sg[nt];
        float u = (float)accu[mt][nt][r] * si * su[nt];
        float a = g / (1.0f + expf(-g)) * u;
        if (valid) arow[ncol[nt]] = __float2bfloat16(a);
        am = fmaxf(am, fabsf(a));
      }
      for (int s = 1; s < 16; s <<= 1) am = fmaxf(am, __shfl_xor(am, s, 16));
      if (valid && ln == 0) atomicMax(amax + prow, __float_as_uint(am));
    }
  }
}

// ---------------------------------------------------------------------------
// Per-row dynamic int8 quant of act (bf16) -> tiled qx2[pmb][kc(22)][64][64]
// ---------------------------------------------------------------------------
__global__ __launch_bounds__(256) void quant_act(
    const __hip_bfloat16* __restrict__ act, const unsigned int* __restrict__ amax,
    const int* __restrict__ cnt, const int* __restrict__ poff,
    signed char* __restrict__ qx2, float* __restrict__ s_a) {
  const int e = blockIdx.y;
  const int ce = cnt[e];
  const int m0 = blockIdx.x * 64;
  if (m0 >= ce) return;
  const int pmb = (poff[e] >> 6) + blockIdx.x;
  const int tid = threadIdx.x;
  const int row = tid >> 2, seg = tid & 3;
  const int mrel = m0 + row;
  const bool valid = mrel < ce;
  const size_t prow = (size_t)poff[e] + mrel;
  float s = fmaxf(__uint_as_float(amax[prow]) / 127.0f, 1e-8f);
  if (valid && seg == 0) s_a[prow] = s;
  const unsigned short* arow = (const unsigned short*)(act + prow * I_DIM) + seg * 16;
  signed char* dstb = qx2 + (size_t)pmb * (22 * 4096) + tid * 16;
  for (int kc = 0; kc < 22; kc++) {
    union { int4 v[2]; unsigned short u[16]; } in;
    union { signed char c[16]; int4 v; } pk;
    if (valid) {
      in.v[0] = *(const int4*)(arow + kc * 64);
      in.v[1] = *(const int4*)(arow + kc * 64 + 8);
#pragma unroll
      for (int j = 0; j < 16; j++) {
        float f = __uint_as_float((unsigned)in.u[j] << 16);
        float q = rintf(f / s);
        q = fminf(127.f, fmaxf(-127.f, q));
        pk.c[j] = (signed char)q;
      }
    } else {
      pk.v = int4{0, 0, 0, 0};
    }
    *(int4*)(dstb + kc * 4096) = pk.v;
  }
}

// ---------------------------------------------------------------------------
// GEMM2: 64x128 tile, tiled staging. h2s plain stores (padded row space).
// ---------------------------------------------------------------------------
__global__ __launch_bounds__(256, 4) void gemm2_h2(
    const signed char* __restrict__ qw2t, const signed char* __restrict__ qx2,
    const float* __restrict__ s_a, const float* __restrict__ s2w,
    const int* __restrict__ cnt, const int* __restrict__ poff,
    float* __restrict__ h2s) {
  const int e = blockIdx.z;
  const int ce = cnt[e];
  const int m0 = blockIdx.x * 64;
  if (m0 >= ce) return;
  const int nb = blockIdx.y;                 // 0..15
  const int n0 = nb * 128;
  const int pmb = (poff[e] >> 6) + blockIdx.x;

  __shared__ __align__(16) signed char As[4096];
  __shared__ __align__(16) signed char Bs[8192];

  const int tid = threadIdx.x;
  const int lane = tid & 63;
  const int wave = tid >> 6;
  const int quad = lane >> 4;
  const int ln = lane & 15;

  const signed char* Ab = qx2 + (size_t)pmb * (22 * 4096) + tid * 16;
  const signed char* Bb = qw2t + (size_t)(e * 16 + nb) * 22 * 8192 + tid * 16;
  const int ldsu = (tid & ~63) * 16;

  v4i acc[4][2];
  v4i zero = {0, 0, 0, 0};
#pragma unroll
  for (int i = 0; i < 4; i++)
#pragma unroll
    for (int j = 0; j < 2; j++) acc[i][j] = zero;

  for (int kc = 0; kc < 22; kc++) {
    __syncthreads();
    GLD_LDS16(Ab + (size_t)kc * 4096, As + ldsu);
    GLD_LDS16(Bb + (size_t)kc * 8192, Bs + ldsu);
    GLD_LDS16(Bb + (size_t)kc * 8192 + 4096, Bs + 4096 + ldsu);
    __syncthreads();

    v4i af[4], bf[2];
#pragma unroll
    for (int mt = 0; mt < 4; mt++)
      af[mt] = *(const v4i*)(As + (mt * 16 + ln) * 64 + quad * 16);
#pragma unroll
    for (int nt = 0; nt < 2; nt++)
      bf[nt] = *(const v4i*)(Bs + (wave * 32 + nt * 16 + ln) * 64 + quad * 16);
#pragma unroll
    for (int mt = 0; mt < 4; mt++)
#pragma unroll
      for (int nt = 0; nt < 2; nt++)
        acc[mt][nt] = __builtin_amdgcn_mfma_i32_16x16x64_i8(af[mt], bf[nt], acc[mt][nt], 0, 0, 0);
  }

  const float* s2e = s2w + e * H_DIM;
  float sw[2];
  int ncol[2];
#pragma unroll
  for (int nt = 0; nt < 2; nt++) {
    int n = n0 + wave * 32 + nt * 16 + ln;
    ncol[nt] = n;
    sw[nt] = s2e[n];
  }
  const int pbase = poff[e];
#pragma unroll
  for (int mt = 0; mt < 4; mt++) {
#pragma unroll
    for (int r = 0; r < 4; r++) {
      int mrel = m0 + mt * 16 + quad * 4 + r;
      if (mrel >= ce) continue;
      size_t prow = (size_t)(pbase + mrel);
      float sa = s_a[prow];
      float* orow = h2s + prow * H_DIM;
#pragma unroll
      for (int nt = 0; nt < 2; nt++)
        orow[ncol[nt]] = (float)acc[mt][nt][r] * sa * sw[nt];
    }
  }
}

// ---------------------------------------------------------------------------
// Final gather: out[t] = g1 * h2s[r1] + g2 * h2s[r2]
// ---------------------------------------------------------------------------
__global__ __launch_bounds__(256) void gather_out(
    const float* __restrict__ h2s, const int* __restrict__ epos,
    const float* __restrict__ gts, const int* __restrict__ poff,
    float* __restrict__ out) {
  const int t = blockIdx.x;
  int a = epos[2 * t], b = epos[2 * t + 1];
  float g1 = gts[2 * t], g2 = gts[2 * t + 1];
  int r1 = poff[a >> 16] + (a & 0xffff);
  int r2 = poff[b >> 16] + (b & 0xffff);
  const float4* R1 = (const float4*)(h2s + (size_t)r1 * H_DIM);
  const float4* R2 = (const float4*)(h2s + (size_t)r2 * H_DIM);
  float4* O = (float4*)(out + (size_t)t * H_DIM);
  for (int c = threadIdx.x; c < H_DIM / 4; c += 256) {
    float4 x = R1[c], y = R2[c];
    float4 z;
    z.x = g1 * x.x + g2 * y.x;
    z.y = g1 * x.y + g2 * y.y;
    z.z = g1 * x.z + g2 * y.z;
    z.w = g1 * x.w + g2 * y.w;
    O[c] = z;
  }
}

// ---------------------------------------------------------------------------
extern "C" void kernel_launch(void* const* d_in, const int* in_sizes, int n_in,
                              void* d_out, int out_size, void* d_ws, size_t ws_size,
                              hipStream_t stream) {
  const float* hs = (const float*)d_in[0];
  const float* gw = (const float*)d_in[1];
  const int* w13 = (const int*)d_in[2];
  const float* s13 = (const float*)d_in[3];
  const int* w2 = (const int*)d_in[4];
  const float* s2w = (const float*)d_in[5];
  float* out = (float*)d_out;

  const int PR = NMB * 64;  // padded row space (8704)

  char* ws = (char*)d_ws;
  size_t o = 0;
  auto take = [&](size_t b) {
    char* p = ws + o;
    o += (b + 255) & ~(size_t)255;
    return p;
  };
  signed char* qw13t = (signed char*)take((size_t)E_NUM * NI2 * H_DIM);      // 46.1 MB
  signed char* qin = (signed char*)take((size_t)T_TOK * H_DIM);              // 8.4 MB
  signed char* qx1 = (signed char*)take((size_t)PR * H_DIM);                 // 17.8 MB
  float* h2s = (float*)qw13t;  // aliases dead qw13t+qin+qx1 (needs 71.3 <= 72.3 MB)
  __hip_bfloat16* act = (__hip_bfloat16*)take((size_t)PR * I_DIM * 2);       // 24.5 MB
  signed char* qw2t = (signed char*)take((size_t)E_NUM * H_DIM * I_DIM);     // 23.1 MB
  signed char* qx2 = (signed char*)take((size_t)PR * I_DIM);                 // 12.3 MB
  float* sin_ = (float*)take((size_t)T_TOK * 4);
  float* sa = (float*)take((size_t)PR * 4);
  unsigned int* amax = (unsigned int*)take((size_t)PR * 4);
  int* tokl = (int*)take((size_t)E_NUM * T_TOK * 4);
  int* tope = (int*)take((size_t)T_TOK * 2 * 4);
  int* epos = (int*)take((size_t)T_TOK * 2 * 4);
  float* gts = (float*)take((size_t)T_TOK * 2 * 4);
  int* cnt = (int*)take(E_NUM * 4);
  int* poff = (int*)take(E_NUM * 4);

  hipMemsetAsync(amax, 0, (size_t)PR * 4, stream);

  pack_tiled<<<8 * 22 * 32 + 8 * 16 * 22, 256, 0, stream>>>(w13, w2, qw13t, qw2t);
  gate_route_quant<<<T_TOK, 256, 0, stream>>>(hs, gw, qin, sin_, tope, gts);
  build_lists<<<E_NUM, 256, 0, stream>>>(tope, tokl, epos, cnt);
  calc_off<<<1, 64, 0, stream>>>(cnt, poff);
  {
    dim3 g(64, 8);
    tile_a1<<<g, 256, 0, stream>>>(qin, tokl, cnt, poff, qx1);
  }
  {
    dim3 g(64, 11, 8);
    gemm1_silu<<<g, 256, 0, stream>>>(qw13t, qx1, sin_, s13, tokl, cnt, poff, act, amax);
  }
  {
    dim3 g(64, 8);
    quant_act<<<g, 256, 0, stream>>>(act, amax, cnt, poff, qx2, sa);
  }
  {
    dim3 g(64, 16, 8);
    gemm2_h2<<<g, 256, 0, stream>>>(qw2t, qx2, sa, s2w, cnt, poff, h2s);
  }
  gather_out<<<T_TOK, 256, 0, stream>>>(h2s, epos, gts, poff, out);
}

// Round 7
// 606.504 us; speedup vs baseline: 1.7430x; 1.1086x over previous
//
#include <hip/hip_runtime.h>
#include <hip/hip_bf16.h>

#define T_TOK 4096
#define H_DIM 2048
#define I_DIM 1408
#define E_NUM 8
#define NI2   (2 * I_DIM)   // 2816
#define NMB   136           // max padded m-blocks

typedef int v4i __attribute__((ext_vector_type(4)));

#define GLD_LDS16(gptr, lptr)                                                        \
  __builtin_amdgcn_global_load_lds(                                                  \
      (const __attribute__((address_space(1))) void*)(gptr),                         \
      (__attribute__((address_space(3))) void*)(lptr), 16, 0, 0)

// ---------------------------------------------------------------------------
// Pack int32 -> int8, TILED: [128 rows][64 k] tiles of 8 KB, contiguous.
// w13: e(8) x nb(22) x kc(32) ; w2: e(8) x nb(16) x kc(22)
// ---------------------------------------------------------------------------
__global__ __launch_bounds__(256) void pack_tiled(
    const int* __restrict__ w13, const int* __restrict__ w2,
    signed char* __restrict__ qw13t, signed char* __restrict__ qw2t) {
  const int id = blockIdx.x;
  const int* src;
  signed char* dst;
  int R, Kd, nb, kc, e;
  if (id < 8 * 22 * 32) {
    e = id / (22 * 32);
    int r = id % (22 * 32);
    nb = r / 32; kc = r % 32;
    src = w13; dst = qw13t + (size_t)id * 8192; R = NI2; Kd = H_DIM;
  } else {
    int j = id - 8 * 22 * 32;
    e = j / (16 * 22);
    int r = j % (16 * 22);
    nb = r / 22; kc = r % 22;
    src = w2; dst = qw2t + (size_t)j * 8192; R = H_DIM; Kd = I_DIM;
  }
  const int tid = threadIdx.x;
  const int seg = tid & 3;
#pragma unroll
  for (int h = 0; h < 2; h++) {
    int row = h * 64 + (tid >> 2);
    const int4* s4 = (const int4*)(src + ((size_t)(e * R + nb * 128 + row) * Kd + kc * 64 + seg * 16));
    int4 v0 = s4[0], v1 = s4[1], v2 = s4[2], v3 = s4[3];
    union { signed char c[16]; int4 v; } pk;
    pk.c[0] = (signed char)v0.x;  pk.c[1] = (signed char)v0.y;
    pk.c[2] = (signed char)v0.z;  pk.c[3] = (signed char)v0.w;
    pk.c[4] = (signed char)v1.x;  pk.c[5] = (signed char)v1.y;
    pk.c[6] = (signed char)v1.z;  pk.c[7] = (signed char)v1.w;
    pk.c[8] = (signed char)v2.x;  pk.c[9] = (signed char)v2.y;
    pk.c[10] = (signed char)v2.z; pk.c[11] = (signed char)v2.w;
    pk.c[12] = (signed char)v3.x; pk.c[13] = (signed char)v3.y;
    pk.c[14] = (signed char)v3.z; pk.c[15] = (signed char)v3.w;
    *(int4*)(dst + h * 4096 + tid * 16) = pk.v;
  }
}

// ---------------------------------------------------------------------------
// Gate logits + top-2 + dynamic int8 quant of hidden_states.
// ---------------------------------------------------------------------------
__global__ __launch_bounds__(256) void gate_route_quant(
    const float* __restrict__ hs, const float* __restrict__ gw,
    signed char* __restrict__ qin, float* __restrict__ s_in,
    int* __restrict__ tope, float* __restrict__ gts) {
  const int t = blockIdx.x;
  const int tid = threadIdx.x;
  const int lane = tid & 63;
  const int wave = tid >> 6;
  const float* row = hs + (size_t)t * H_DIM;

  const float4* r4 = (const float4*)row + tid * 2;
  float4 xa = r4[0], xb = r4[1];
  float x[8] = {xa.x, xa.y, xa.z, xa.w, xb.x, xb.y, xb.z, xb.w};

  double pd[8];
  for (int e = 0; e < 8; e++) pd[e] = 0.0;
  float am = 0.f;
  for (int j = 0; j < 8; j++) {
    float v = x[j];
    am = fmaxf(am, fabsf(v));
    int col = tid * 8 + j;
    for (int e = 0; e < 8; e++)
      pd[e] += (double)v * (double)gw[e * H_DIM + col];
  }
  for (int e = 0; e < 8; e++)
    for (int s = 32; s; s >>= 1) pd[e] += __shfl_down(pd[e], s);
  for (int s = 32; s; s >>= 1) am = fmaxf(am, __shfl_down(am, s));

  __shared__ double sred[4][8];
  __shared__ float sam[4];
  __shared__ float sbc;
  if (lane == 0) {
    for (int e = 0; e < 8; e++) sred[wave][e] = pd[e];
    sam[wave] = am;
  }
  __syncthreads();
  if (tid == 0) {
    float l[8];
    for (int e = 0; e < 8; e++)
      l[e] = (float)(sred[0][e] + sred[1][e] + sred[2][e] + sred[3][e]);
    float amx = fmaxf(fmaxf(sam[0], sam[1]), fmaxf(sam[2], sam[3]));
    float s = fmaxf(amx / 127.0f, 1e-8f);
    s_in[t] = s;
    sbc = s;
    int i1 = 0;
    for (int e = 1; e < 8; e++) if (l[e] > l[i1]) i1 = e;
    int i2 = -1;
    for (int e = 0; e < 8; e++) {
      if (e == i1) continue;
      if (i2 < 0 || l[e] > l[i2]) i2 = e;
    }
    float d = expf(l[i2] - l[i1]);
    tope[2 * t] = i1;     gts[2 * t] = 1.0f / (1.0f + d);
    tope[2 * t + 1] = i2; gts[2 * t + 1] = d / (1.0f + d);
  }
  __syncthreads();
  float s = sbc;
  union { signed char c[8]; unsigned long long u; } pk;
  for (int j = 0; j < 8; j++) {
    float q = rintf(x[j] / s);
    q = fminf(127.f, fmaxf(-127.f, q));
    pk.c[j] = (signed char)q;
  }
  ((unsigned long long*)(qin + (size_t)t * H_DIM))[tid] = pk.u;
}

// ---------------------------------------------------------------------------
// Build per-expert token lists deterministically (ballot prefix, no atomics).
// ---------------------------------------------------------------------------
__global__ __launch_bounds__(256) void build_lists(
    const int* __restrict__ tope, int* __restrict__ tok_list,
    int* __restrict__ epos, int* __restrict__ cnt) {
  const int e = blockIdx.x;
  const int tid = threadIdx.x;
  const int lane = tid & 63;
  const int wave = tid >> 6;
  __shared__ int wsum[4];
  __shared__ int base_s;
  if (tid == 0) base_s = 0;
  __syncthreads();
  for (int t0 = 0; t0 < T_TOK; t0 += 256) {
    int t = t0 + tid;
    int i1 = tope[2 * t], i2 = tope[2 * t + 1];
    int slot = (i1 == e) ? 0 : ((i2 == e) ? 1 : -1);
    unsigned long long m = __ballot(slot >= 0);
    int wpre = __popcll(m & ((1ull << lane) - 1ull));
    if (lane == 0) wsum[wave] = __popcll(m);
    __syncthreads();
    int pre = wpre;
    for (int w = 0; w < wave; w++) pre += wsum[w];
    int total = wsum[0] + wsum[1] + wsum[2] + wsum[3];
    int b = base_s;
    if (slot >= 0) {
      int pos = b + pre;
      tok_list[e * T_TOK + pos] = t;
      epos[2 * t + slot] = (e << 16) | pos;
    }
    __syncthreads();
    if (tid == 0) base_s = b + total;
  }
  __syncthreads();
  if (tid == 0) cnt[e] = base_s;
}

__global__ void calc_off(const int* __restrict__ cnt, int* __restrict__ poff) {
  if (threadIdx.x == 0) {
    int p = 0;
    for (int e = 0; e < E_NUM; e++) {
      poff[e] = p;
      p += ((cnt[e] + 63) >> 6) << 6;
    }
  }
}

// ---------------------------------------------------------------------------
// Gather routed token rows into tiled A: qx1[pmb][kc(32)][64 rows][64 B]
// ---------------------------------------------------------------------------
__global__ __launch_bounds__(256) void tile_a1(
    const signed char* __restrict__ qin, const int* __restrict__ tok_list,
    const int* __restrict__ cnt, const int* __restrict__ poff,
    signed char* __restrict__ qx1) {
  const int e = blockIdx.y;
  const int ce = cnt[e];
  const int m0 = blockIdx.x * 64;
  if (m0 >= ce) return;
  const int pmb = (poff[e] >> 6) + blockIdx.x;
  const int tid = threadIdx.x;
  const int row = tid >> 2, seg = tid & 3;
  const int tok = tok_list[e * T_TOK + min(m0 + row, ce - 1)];
  const signed char* src = qin + (size_t)tok * H_DIM + seg * 16;
  signed char* dstb = qx1 + (size_t)pmb * (32 * 4096) + tid * 16;
#pragma unroll
  for (int kc = 0; kc < 32; kc++)
    *(int4*)(dstb + kc * 4096) = *(const int4*)(src + kc * 64);
}

// ---------------------------------------------------------------------------
// GEMM1: 64x128 tile, tiled staging, two-barrier K-loop, XCD-PINNED dispatch.
// id = xcd + 8*(sl*64 + mb); slice s = xcd + 8*sl (0..87); e = s/11, nb = s%11.
// All m-blocks of one (e,nb) B-slice run consecutively on ONE XCD ->
// 512 KB slice stays L2-resident, L3/HBM traffic ~compulsory.
// ---------------------------------------------------------------------------
__global__ __launch_bounds__(256, 3) void gemm1_silu(
    const signed char* __restrict__ qw13t, const signed char* __restrict__ qx1,
    const float* __restrict__ s_in, const float* __restrict__ s13,
    const int* __restrict__ tok_list, const int* __restrict__ cnt,
    const int* __restrict__ poff, __hip_bfloat16* __restrict__ act,
    unsigned int* __restrict__ amax) {
  const int xcd = blockIdx.x & 7;
  const int r = blockIdx.x >> 3;
  const int sl = r >> 6;                 // 0..10
  const int mb = r & 63;
  const int s = xcd + 8 * sl;            // 0..87
  const int e = s / 11;
  const int nb = s % 11;

  const int ce = cnt[e];
  const int m0 = mb * 64;
  if (m0 >= ce) return;
  const int n0 = nb * 128;
  const int pmb = (poff[e] >> 6) + mb;

  __shared__ __align__(16) signed char As[4096];
  __shared__ __align__(16) signed char Bg[8192];
  __shared__ __align__(16) signed char Bu[8192];

  const int tid = threadIdx.x;
  const int lane = tid & 63;
  const int wave = tid >> 6;
  const int quad = lane >> 4;
  const int ln = lane & 15;

  const signed char* Ab = qx1 + (size_t)pmb * (32 * 4096) + tid * 16;
  const signed char* Bgb = qw13t + (size_t)(e * 22 + nb) * 32 * 8192 + tid * 16;
  const signed char* Bub = qw13t + (size_t)(e * 22 + nb + 11) * 32 * 8192 + tid * 16;
  const int ldsu = (tid & ~63) * 16;

  v4i accg[4][2], accu[4][2];
  v4i zero = {0, 0, 0, 0};
#pragma unroll
  for (int i = 0; i < 4; i++)
#pragma unroll
    for (int j = 0; j < 2; j++) { accg[i][j] = zero; accu[i][j] = zero; }

  for (int kc = 0; kc < 32; kc++) {
    __syncthreads();
    GLD_LDS16(Ab + (size_t)kc * 4096, As + ldsu);
    GLD_LDS16(Bgb + (size_t)kc * 8192, Bg + ldsu);
    GLD_LDS16(Bgb + (size_t)kc * 8192 + 4096, Bg + 4096 + ldsu);
    GLD_LDS16(Bub + (size_t)kc * 8192, Bu + ldsu);
    GLD_LDS16(Bub + (size_t)kc * 8192 + 4096, Bu + 4096 + ldsu);
    __syncthreads();

    v4i af[4], bgf[2], buf_[2];
#pragma unroll
    for (int mt = 0; mt < 4; mt++)
      af[mt] = *(const v4i*)(As + (mt * 16 + ln) * 64 + quad * 16);
#pragma unroll
    for (int nt = 0; nt < 2; nt++) {
      bgf[nt] = *(const v4i*)(Bg + (wave * 32 + nt * 16 + ln) * 64 + quad * 16);
      buf_[nt] = *(const v4i*)(Bu + (wave * 32 + nt * 16 + ln) * 64 + quad * 16);
    }
#pragma unroll
    for (int mt = 0; mt < 4; mt++)
#pragma unroll
      for (int nt = 0; nt < 2; nt++) {
        accg[mt][nt] = __builtin_amdgcn_mfma_i32_16x16x64_i8(af[mt], bgf[nt], accg[mt][nt], 0, 0, 0);
        accu[mt][nt] = __builtin_amdgcn_mfma_i32_16x16x64_i8(af[mt], buf_[nt], accu[mt][nt], 0, 0, 0);
      }
  }

  const float* s13e = s13 + e * NI2;
  float sg[2], su[2];
  int ncol[2];
#pragma unroll
  for (int nt = 0; nt < 2; nt++) {
    int n = n0 + wave * 32 + nt * 16 + ln;
    ncol[nt] = n;
    sg[nt] = s13e[n];
    su[nt] = s13e[I_DIM + n];
  }
  const int* tl = tok_list + e * T_TOK;
  const int pbase = poff[e];
#pragma unroll
  for (int mt = 0; mt < 4; mt++) {
#pragma unroll
    for (int r2 = 0; r2 < 4; r2++) {
      int mrel = m0 + mt * 16 + quad * 4 + r2;
      bool valid = mrel < ce;
      int tok = tl[valid ? mrel : 0];
      float si = s_in[tok];
      size_t prow = (size_t)(pbase + mrel);
      __hip_bfloat16* arow = act + prow * I_DIM;
      float am = 0.f;
#pragma unroll
      for (int nt = 0; nt < 2; nt++) {
        float g = (float)accg[mt][nt][r2] * si * sg[nt];
        float u = (float)accu[mt][nt][r2] * si * su[nt];
        float a = g / (1.0f + expf(-g)) * u;
        if (valid) arow[ncol[nt]] = __float2bfloat16(a);
        am = fmaxf(am, fabsf(a));
      }
      for (int sh = 1; sh < 16; sh <<= 1) am = fmaxf(am, __shfl_xor(am, sh, 16));
      if (valid && ln == 0) atomicMax(amax + prow, __float_as_uint(am));
    }
  }
}

// ---------------------------------------------------------------------------
// Per-row dynamic int8 quant of act (bf16) -> tiled qx2[pmb][kc(22)][64][64]
// ---------------------------------------------------------------------------
__global__ __launch_bounds__(256) void quant_act(
    const __hip_bfloat16* __restrict__ act, const unsigned int* __restrict__ amax,
    const int* __restrict__ cnt, const int* __restrict__ poff,
    signed char* __restrict__ qx2, float* __restrict__ s_a) {
  const int e = blockIdx.y;
  const int ce = cnt[e];
  const int m0 = blockIdx.x * 64;
  if (m0 >= ce) return;
  const int pmb = (poff[e] >> 6) + blockIdx.x;
  const int tid = threadIdx.x;
  const int row = tid >> 2, seg = tid & 3;
  const int mrel = m0 + row;
  const bool valid = mrel < ce;
  const size_t prow = (size_t)poff[e] + mrel;
  float s = fmaxf(__uint_as_float(amax[prow]) / 127.0f, 1e-8f);
  if (valid && seg == 0) s_a[prow] = s;
  const unsigned short* arow = (const unsigned short*)(act + prow * I_DIM) + seg * 16;
  signed char* dstb = qx2 + (size_t)pmb * (22 * 4096) + tid * 16;
  for (int kc = 0; kc < 22; kc++) {
    union { int4 v[2]; unsigned short u[16]; } in;
    union { signed char c[16]; int4 v; } pk;
    if (valid) {
      in.v[0] = *(const int4*)(arow + kc * 64);
      in.v[1] = *(const int4*)(arow + kc * 64 + 8);
#pragma unroll
      for (int j = 0; j < 16; j++) {
        float f = __uint_as_float((unsigned)in.u[j] << 16);
        float q = rintf(f / s);
        q = fminf(127.f, fmaxf(-127.f, q));
        pk.c[j] = (signed char)q;
      }
    } else {
      pk.v = int4{0, 0, 0, 0};
    }
    *(int4*)(dstb + kc * 4096) = pk.v;
  }
}

// ---------------------------------------------------------------------------
// GEMM2: 64x128 tile, tiled staging, XCD-PINNED dispatch.
// id = xcd + 8*(sl*64 + mb); slice s = xcd + 8*sl (0..127); e = s>>4, nb = s&15.
// ---------------------------------------------------------------------------
__global__ __launch_bounds__(256, 4) void gemm2_h2(
    const signed char* __restrict__ qw2t, const signed char* __restrict__ qx2,
    const float* __restrict__ s_a, const float* __restrict__ s2w,
    const int* __restrict__ cnt, const int* __restrict__ poff,
    float* __restrict__ h2s) {
  const int xcd = blockIdx.x & 7;
  const int r = blockIdx.x >> 3;
  const int sl = r >> 6;                 // 0..15
  const int mb = r & 63;
  const int s = xcd + 8 * sl;            // 0..127
  const int e = s >> 4;
  const int nb = s & 15;

  const int ce = cnt[e];
  const int m0 = mb * 64;
  if (m0 >= ce) return;
  const int n0 = nb * 128;
  const int pmb = (poff[e] >> 6) + mb;

  __shared__ __align__(16) signed char As[4096];
  __shared__ __align__(16) signed char Bs[8192];

  const int tid = threadIdx.x;
  const int lane = tid & 63;
  const int wave = tid >> 6;
  const int quad = lane >> 4;
  const int ln = lane & 15;

  const signed char* Ab = qx2 + (size_t)pmb * (22 * 4096) + tid * 16;
  const signed char* Bb = qw2t + (size_t)(e * 16 + nb) * 22 * 8192 + tid * 16;
  const int ldsu = (tid & ~63) * 16;

  v4i acc[4][2];
  v4i zero = {0, 0, 0, 0};
#pragma unroll
  for (int i = 0; i < 4; i++)
#pragma unroll
    for (int j = 0; j < 2; j++) acc[i][j] = zero;

  for (int kc = 0; kc < 22; kc++) {
    __syncthreads();
    GLD_LDS16(Ab + (size_t)kc * 4096, As + ldsu);
    GLD_LDS16(Bb + (size_t)kc * 8192, Bs + ldsu);
    GLD_LDS16(Bb + (size_t)kc * 8192 + 4096, Bs + 4096 + ldsu);
    __syncthreads();

    v4i af[4], bf[2];
#pragma unroll
    for (int mt = 0; mt < 4; mt++)
      af[mt] = *(const v4i*)(As + (mt * 16 + ln) * 64 + quad * 16);
#pragma unroll
    for (int nt = 0; nt < 2; nt++)
      bf[nt] = *(const v4i*)(Bs + (wave * 32 + nt * 16 + ln) * 64 + quad * 16);
#pragma unroll
    for (int mt = 0; mt < 4; mt++)
#pragma unroll
      for (int nt = 0; nt < 2; nt++)
        acc[mt][nt] = __builtin_amdgcn_mfma_i32_16x16x64_i8(af[mt], bf[nt], acc[mt][nt], 0, 0, 0);
  }

  const float* s2e = s2w + e * H_DIM;
  float sw[2];
  int ncol[2];
#pragma unroll
  for (int nt = 0; nt < 2; nt++) {
    int n = n0 + wave * 32 + nt * 16 + ln;
    ncol[nt] = n;
    sw[nt] = s2e[n];
  }
  const int pbase = poff[e];
#pragma unroll
  for (int mt = 0; mt < 4; mt++) {
#pragma unroll
    for (int r2 = 0; r2 < 4; r2++) {
      int mrel = m0 + mt * 16 + quad * 4 + r2;
      if (mrel >= ce) continue;
      size_t prow = (size_t)(pbase + mrel);
      float sa = s_a[prow];
      float* orow = h2s + prow * H_DIM;
#pragma unroll
      for (int nt = 0; nt < 2; nt++)
        orow[ncol[nt]] = (float)acc[mt][nt][r2] * sa * sw[nt];
    }
  }
}

// ---------------------------------------------------------------------------
// Final gather: out[t] = g1 * h2s[r1] + g2 * h2s[r2]
// ---------------------------------------------------------------------------
__global__ __launch_bounds__(256) void gather_out(
    const float* __restrict__ h2s, const int* __restrict__ epos,
    const float* __restrict__ gts, const int* __restrict__ poff,
    float* __restrict__ out) {
  const int t = blockIdx.x;
  int a = epos[2 * t], b = epos[2 * t + 1];
  float g1 = gts[2 * t], g2 = gts[2 * t + 1];
  int r1 = poff[a >> 16] + (a & 0xffff);
  int r2 = poff[b >> 16] + (b & 0xffff);
  const float4* R1 = (const float4*)(h2s + (size_t)r1 * H_DIM);
  const float4* R2 = (const float4*)(h2s + (size_t)r2 * H_DIM);
  float4* O = (float4*)(out + (size_t)t * H_DIM);
  for (int c = threadIdx.x; c < H_DIM / 4; c += 256) {
    float4 x = R1[c], y = R2[c];
    float4 z;
    z.x = g1 * x.x + g2 * y.x;
    z.y = g1 * x.y + g2 * y.y;
    z.z = g1 * x.z + g2 * y.z;
    z.w = g1 * x.w + g2 * y.w;
    O[c] = z;
  }
}

// ---------------------------------------------------------------------------
extern "C" void kernel_launch(void* const* d_in, const int* in_sizes, int n_in,
                              void* d_out, int out_size, void* d_ws, size_t ws_size,
                              hipStream_t stream) {
  const float* hs = (const float*)d_in[0];
  const float* gw = (const float*)d_in[1];
  const int* w13 = (const int*)d_in[2];
  const float* s13 = (const float*)d_in[3];
  const int* w2 = (const int*)d_in[4];
  const float* s2w = (const float*)d_in[5];
  float* out = (float*)d_out;

  const int PR = NMB * 64;  // padded row space (8704)

  char* ws = (char*)d_ws;
  size_t o = 0;
  auto take = [&](size_t b) {
    char* p = ws + o;
    o += (b + 255) & ~(size_t)255;
    return p;
  };
  signed char* qw13t = (signed char*)take((size_t)E_NUM * NI2 * H_DIM);      // 46.1 MB
  signed char* qin = (signed char*)take((size_t)T_TOK * H_DIM);              // 8.4 MB
  signed char* qx1 = (signed char*)take((size_t)PR * H_DIM);                 // 17.8 MB
  float* h2s = (float*)qw13t;  // aliases dead qw13t+qin+qx1 (needs 71.3 <= 72.3 MB)
  __hip_bfloat16* act = (__hip_bfloat16*)take((size_t)PR * I_DIM * 2);       // 24.5 MB
  signed char* qw2t = (signed char*)take((size_t)E_NUM * H_DIM * I_DIM);     // 23.1 MB
  signed char* qx2 = (signed char*)take((size_t)PR * I_DIM);                 // 12.3 MB
  float* sin_ = (float*)take((size_t)T_TOK * 4);
  float* sa = (float*)take((size_t)PR * 4);
  unsigned int* amax = (unsigned int*)take((size_t)PR * 4);
  int* tokl = (int*)take((size_t)E_NUM * T_TOK * 4);
  int* tope = (int*)take((size_t)T_TOK * 2 * 4);
  int* epos = (int*)take((size_t)T_TOK * 2 * 4);
  float* gts = (float*)take((size_t)T_TOK * 2 * 4);
  int* cnt = (int*)take(E_NUM * 4);
  int* poff = (int*)take(E_NUM * 4);

  hipMemsetAsync(amax, 0, (size_t)PR * 4, stream);

  pack_tiled<<<8 * 22 * 32 + 8 * 16 * 22, 256, 0, stream>>>(w13, w2, qw13t, qw2t);
  gate_route_quant<<<T_TOK, 256, 0, stream>>>(hs, gw, qin, sin_, tope, gts);
  build_lists<<<E_NUM, 256, 0, stream>>>(tope, tokl, epos, cnt);
  calc_off<<<1, 64, 0, stream>>>(cnt, poff);
  {
    dim3 g(64, 8);
    tile_a1<<<g, 256, 0, stream>>>(qin, tokl, cnt, poff, qx1);
  }
  gemm1_silu<<<8 * 11 * 64, 256, 0, stream>>>(qw13t, qx1, sin_, s13, tokl, cnt, poff, act, amax);
  {
    dim3 g(64, 8);
    quant_act<<<g, 256, 0, stream>>>(act, amax, cnt, poff, qx2, sa);
  }
  gemm2_h2<<<8 * 16 * 64, 256, 0, stream>>>(qw2t, qx2, sa, s2w, cnt, poff, h2s);
  gather_out<<<T_TOK, 256, 0, stream>>>(h2s, epos, gts, poff, out);
}